// Round 11
// baseline (618.003 us; speedup 1.0000x reference)
//
#include <hip/hip_runtime.h>
#include <hip/hip_bf16.h>

#define F_DIM 128
#define N_RBF 20
#define CUTOFF 5.0f
#define PI_F 3.14159265358979323846f
#define NPB 4   // nodes per k_edge block

typedef float v2f __attribute__((ext_vector_type(2)));
typedef __attribute__((ext_vector_type(8))) short bf16x8;
typedef __attribute__((ext_vector_type(4))) float f32x4;

__device__ __forceinline__ unsigned int bf16_rtne(float f) {
    unsigned int u = __float_as_uint(f);
    u += 0x7fffu + ((u >> 16) & 1u);
    return u >> 16;
}
__device__ __forceinline__ unsigned int pack_bf2(float lo, float hi) {
    return bf16_rtne(lo) | (bf16_rtne(hi) << 16);
}
__device__ __forceinline__ float unpk_lo(unsigned int u) {
    return __uint_as_float(u << 16);
}
__device__ __forceinline__ float unpk_hi(unsigned int u) {
    return __uint_as_float(u & 0xffff0000u);
}
__device__ __forceinline__ float bf16_to_f(unsigned short s) {
    return __uint_as_float(((unsigned int)s) << 16);
}

// ---------------------------------------------------------------------------
__global__ __launch_bounds__(256) void k_rowptr(const int* __restrict__ idx_i,
                                                int* __restrict__ row_ptr, int N, int E) {
    int i = blockIdx.x * blockDim.x + threadIdx.x;
    if (i > N) return;
    if (i == N) { row_ptr[N] = E; return; }
    int lo = 0, hi = E;
    while (lo < hi) {
        int mid = (lo + hi) >> 1;
        if (idx_i[mid] < i) lo = mid + 1; else hi = mid;
    }
    row_ptr[i] = lo;
}

// ---------------------------------------------------------------------------
__global__ __launch_bounds__(256) void k_init(const int* __restrict__ Z,
                                              const float* __restrict__ emb,
                                              float* __restrict__ q,
                                              unsigned int* __restrict__ P,
                                              float* __restrict__ muD, int N) {
    int idx = blockIdx.x * blockDim.x + threadIdx.x;
    if (idx < N * F_DIM) {
        int n = idx >> 7, f = idx & 127;
        q[idx] = emb[Z[n] * F_DIM + f];
    }
    if (idx < N * 384) { P[idx] = 0u; muD[idx] = 0.f; }
}

// ---------------------------------------------------------------------------
__global__ __launch_bounds__(256) void k_prep(const float* __restrict__ muxW,
                                              const float* __restrict__ W1,
                                              const float* __restrict__ W2,
                                              const float* __restrict__ iW1,
                                              const float* __restrict__ iW2,
                                              unsigned short* __restrict__ muxWt,
                                              unsigned short* __restrict__ W1t,
                                              unsigned short* __restrict__ W2t,
                                              unsigned short* __restrict__ iW1t,
                                              unsigned short* __restrict__ iW2t) {
    int idx = blockIdx.x * 256 + threadIdx.x;
    if (idx < 98304) {                     // muxWt[l][c<256][k<128]
        int l = idx / 32768, rem = idx % 32768;
        int c = rem / 128, k = rem % 128;
        muxWt[idx] = (unsigned short)bf16_rtne(muxW[l * 32768 + k * 256 + c]);
    } else if (idx < 196608) {             // W1t[l][c<128][k<256]
        int i2 = idx - 98304;
        int l = i2 / 32768, rem = i2 % 32768;
        int c = rem / 256, k = rem % 256;
        W1t[i2] = (unsigned short)bf16_rtne(W1[l * 32768 + k * 128 + c]);
    } else if (idx < 344064) {             // W2t[l][c<384][k<128]
        int i2 = idx - 196608;
        int l = i2 / 49152, rem = i2 % 49152;
        int c = rem / 128, k = rem % 128;
        W2t[i2] = (unsigned short)bf16_rtne(W2[l * 49152 + k * 384 + c]);
    } else if (idx < 393216) {             // iW1t[l][c<128][k<128]
        int i2 = idx - 344064;
        int l = i2 / 16384, rem = i2 % 16384;
        int c = rem / 128, k = rem % 128;
        iW1t[i2] = (unsigned short)bf16_rtne(iW1[l * 16384 + k * 128 + c]);
    } else if (idx < 540672) {             // iW2t[l][c<384][k<128]
        int i2 = idx - 393216;
        int l = i2 / 49152, rem = i2 % 49152;
        int c = rem / 128, k = rem % 128;
        iW2t[i2] = (unsigned short)bf16_rtne(iW2[l * 49152 + k * 384 + c]);
    }
}

// ---------------------------------------------------------------------------
__global__ __launch_bounds__(256) void k_geom(const float* __restrict__ r,
                                              float* __restrict__ geom, int E) {
    int e = blockIdx.x * blockDim.x + threadIdx.x;
    if (e >= E) return;
    float x = r[e * 3], y = r[e * 3 + 1], z = r[e * 3 + 2];
    float d = sqrtf(x * x + y * y + z * z);
    float inv = 1.f / d;
    float fc = (d < CUTOFF) ? 0.5f * (__cosf(d * (PI_F / CUTOFF)) + 1.f) : 0.f;
    float* g = geom + (size_t)e * 24;
    g[0] = x * inv; g[1] = y * inv; g[2] = z * inv; g[3] = fc;
    const float delta = CUTOFF / (N_RBF - 1);
    const float coeff = -0.5f / (delta * delta);
#pragma unroll
    for (int k = 0; k < N_RBF; k++) {
        float t = d - k * delta;
        g[4 + k] = __expf(coeff * t * t) * fc;
    }
}

// ---------------------------------------------------------------------------
// Node message MLP via MFMA (layer 0 only). 4 waves per 16-node tile.
__global__ __launch_bounds__(256) void k_node_mfma(
        const float* __restrict__ q,
        const unsigned short* __restrict__ iW1t,   // [128][128] bf16 (c,k)
        const float* __restrict__ b1,
        const unsigned short* __restrict__ iW2t,   // [384][128]
        const float* __restrict__ b2,
        unsigned int* __restrict__ P, int N) {
    __shared__ unsigned short A[16 * 136];
    __shared__ unsigned short Ah[16 * 136];
    __shared__ float Xs[16 * 396];
    int t = threadIdx.x;
    int w = t >> 6, l = t & 63, quad = l >> 4, c0 = l & 15;
    int n0 = blockIdx.x * 16;

#pragma unroll
    for (int i = 0; i < 4; i++) {
        int flat = i * 256 + t;
        int node = flat >> 6, cp = flat & 63;
        int gn = n0 + node;
        unsigned int v = 0u;
        if (gn < N) { const float* s = q + (size_t)gn * 128 + 2 * cp; v = pack_bf2(s[0], s[1]); }
        *(unsigned int*)&A[node * 136 + 2 * cp] = v;
    }
    __syncthreads();

    bf16x8 a1[4];
#pragma unroll
    for (int ks = 0; ks < 4; ks++)
        a1[ks] = *(const bf16x8*)&A[c0 * 136 + ks * 32 + quad * 8];
#pragma unroll
    for (int jj = 0; jj < 2; jj++) {
        int jg = 2 * w + jj;
        float bb = b1[16 * jg + c0];
        f32x4 acc = (f32x4){bb, bb, bb, bb};
#pragma unroll
        for (int ks = 0; ks < 4; ks++) {
            bf16x8 b = *(const bf16x8*)&iW1t[(16 * jg + c0) * 128 + ks * 32 + quad * 8];
            acc = __builtin_amdgcn_mfma_f32_16x16x32_bf16(a1[ks], b, acc, 0, 0, 0);
        }
#pragma unroll
        for (int r = 0; r < 4; r++) {
            float aa = acc[r];
            Ah[(quad * 4 + r) * 136 + 16 * jg + c0] =
                (unsigned short)bf16_rtne(aa / (1.f + __expf(-aa)));
        }
    }
    __syncthreads();

    bf16x8 a3[4];
#pragma unroll
    for (int ks = 0; ks < 4; ks++)
        a3[ks] = *(const bf16x8*)&Ah[c0 * 136 + ks * 32 + quad * 8];
#pragma unroll
    for (int jj = 0; jj < 6; jj++) {
        int jx = 6 * w + jj;
        float bb = b2[16 * jx + c0];
        f32x4 acc = (f32x4){bb, bb, bb, bb};
#pragma unroll
        for (int ks = 0; ks < 4; ks++) {
            bf16x8 b = *(const bf16x8*)&iW2t[(16 * jx + c0) * 128 + ks * 32 + quad * 8];
            acc = __builtin_amdgcn_mfma_f32_16x16x32_bf16(a3[ks], b, acc, 0, 0, 0);
        }
#pragma unroll
        for (int r = 0; r < 4; r++)
            Xs[(quad * 4 + r) * 396 + 16 * jx + c0] = acc[r];
    }
    __syncthreads();

    int n = t >> 4, fi = (t & 15) * 8;
    int gn = n0 + n;
    if (gn < N) {
        size_t base = (size_t)gn * 384;
        unsigned int d[8];
#pragma unroll
        for (int k = 0; k < 8; k++) {
            float x0 = Xs[n * 396 + fi + k];
            float x1 = Xs[n * 396 + 128 + fi + k];
            float x2 = Xs[n * 396 + 256 + fi + k];
            d[k] = pack_bf2(x0, x1);
            ((unsigned short*)&P[base + 256 + fi + k])[0] = (unsigned short)bf16_rtne(x2);
        }
        *(uint4*)&P[base + fi]     = make_uint4(d[0], d[1], d[2], d[3]);
        *(uint4*)&P[base + fi + 4] = make_uint4(d[4], d[5], d[6], d[7]);
    }
}

// ---------------------------------------------------------------------------
// Edge aggregation. Filter weights asm-pinned into VGPRs (R9 postmortem:
// VGPR_Count=44 proved the compiler was sinking the 63 weight loads into the
// edge loop). 2-edge manual unroll: both edges' gathers issue before either
// filter block, giving ~70 VALU ops of latency cover.
__global__ __launch_bounds__(256, 4) void k_edge(
        const unsigned int* __restrict__ P,
        const float* __restrict__ geom,
        const int* __restrict__ idx_j,
        const int* __restrict__ row_ptr,
        const float* __restrict__ filt_W,
        const float* __restrict__ filt_b,
        int layer,
        float* __restrict__ q,
        float* __restrict__ muD, int N) {
    __shared__ float red[4][128];
    int t = threadIdx.x;
    int f = t & 127;
    int sub = __builtin_amdgcn_readfirstlane(t >> 7);

    v2f W0p[N_RBF / 2], W1p[N_RBF / 2], W2p[N_RBF / 2];
    const float* Wbase = filt_W + layer * 384;
#pragma unroll
    for (int j = 0; j < N_RBF / 2; j++) {
        W0p[j] = (v2f){Wbase[(2 * j) * 1152 + f],       Wbase[(2 * j + 1) * 1152 + f]};
        W1p[j] = (v2f){Wbase[(2 * j) * 1152 + 128 + f], Wbase[(2 * j + 1) * 1152 + 128 + f]};
        W2p[j] = (v2f){Wbase[(2 * j) * 1152 + 256 + f], Wbase[(2 * j + 1) * 1152 + 256 + f]};
    }
    float bf0 = filt_b[layer * 384 + f];
    float bf1 = filt_b[layer * 384 + 128 + f];
    float bf2 = filt_b[layer * 384 + 256 + f];
    // Pin weights in VGPRs: opaque asm outputs cannot be rematerialized.
#pragma unroll
    for (int j = 0; j < N_RBF / 2; j++)
        asm volatile("" : "+v"(W0p[j]), "+v"(W1p[j]), "+v"(W2p[j]));
    asm volatile("" : "+v"(bf0), "+v"(bf1), "+v"(bf2));

    int i0 = blockIdx.x * NPB;
    for (int nn = 0; nn < NPB; nn++) {
        int i = i0 + nn;
        if (i >= N) break;
        int rs = __builtin_amdgcn_readfirstlane(row_ptr[i]);
        int re = __builtin_amdgcn_readfirstlane(row_ptr[i + 1]);
        float dq = 0.f;
        v2f dm01 = (v2f){0.f, 0.f};
        float dm2 = 0.f;

        int e = rs + sub;
        // paired iterations: edges e and e+2
        for (; e + 2 < re; e += 4) {
            int j0 = __builtin_amdgcn_readfirstlane(idx_j[e]);
            int j1 = __builtin_amdgcn_readfirstlane(idx_j[e + 2]);
            const unsigned int* Pj0 = P + (size_t)j0 * 384;
            const unsigned int* Pj1 = P + (size_t)j1 * 384;
            unsigned int A0 = Pj0[f], B0 = Pj0[128 + f], C0 = Pj0[256 + f];
            unsigned int A1 = Pj1[f], B1 = Pj1[128 + f], C1 = Pj1[256 + f];
            const float4* g40 = (const float4*)(geom + (size_t)e * 24);
            const float4* g41 = (const float4*)(geom + (size_t)(e + 2) * 24);
            float4 a0 = g40[0];
            float4 q00 = g40[1], q01 = g40[2], q02 = g40[3], q03 = g40[4], q04 = g40[5];
            float4 a1 = g41[0];
            float4 q10 = g41[1], q11 = g41[2], q12 = g41[3], q13 = g41[4], q14 = g41[5];

            {   // edge 0
                v2f ph[N_RBF / 2] = {
                    (v2f){q00.x, q00.y}, (v2f){q00.z, q00.w},
                    (v2f){q01.x, q01.y}, (v2f){q01.z, q01.w},
                    (v2f){q02.x, q02.y}, (v2f){q02.z, q02.w},
                    (v2f){q03.x, q03.y}, (v2f){q03.z, q03.w},
                    (v2f){q04.x, q04.y}, (v2f){q04.z, q04.w}};
                v2f aq = (v2f){0.f, 0.f}, ar = (v2f){0.f, 0.f}, am = (v2f){0.f, 0.f};
#pragma unroll
                for (int k = 0; k < N_RBF / 2; k++) {
                    aq += ph[k] * W0p[k];
                    ar += ph[k] * W1p[k];
                    am += ph[k] * W2p[k];
                }
                float wq = aq.x + aq.y + a0.w * bf0;
                float wr = ar.x + ar.y + a0.w * bf1;
                float wm = am.x + am.y + a0.w * bf2;
                dq += wq * unpk_lo(A0);
                float s_r = wr * unpk_hi(A0), s_m = wm * unpk_lo(C0);
                dm01 += (v2f){s_r, s_r} * (v2f){a0.x, a0.y} +
                        (v2f){s_m, s_m} * (v2f){unpk_lo(B0), unpk_hi(B0)};
                dm2  += s_r * a0.z + s_m * unpk_hi(C0);
            }
            {   // edge 1
                v2f ph[N_RBF / 2] = {
                    (v2f){q10.x, q10.y}, (v2f){q10.z, q10.w},
                    (v2f){q11.x, q11.y}, (v2f){q11.z, q11.w},
                    (v2f){q12.x, q12.y}, (v2f){q12.z, q12.w},
                    (v2f){q13.x, q13.y}, (v2f){q13.z, q13.w},
                    (v2f){q14.x, q14.y}, (v2f){q14.z, q14.w}};
                v2f aq = (v2f){0.f, 0.f}, ar = (v2f){0.f, 0.f}, am = (v2f){0.f, 0.f};
#pragma unroll
                for (int k = 0; k < N_RBF / 2; k++) {
                    aq += ph[k] * W0p[k];
                    ar += ph[k] * W1p[k];
                    am += ph[k] * W2p[k];
                }
                float wq = aq.x + aq.y + a1.w * bf0;
                float wr = ar.x + ar.y + a1.w * bf1;
                float wm = am.x + am.y + a1.w * bf2;
                dq += wq * unpk_lo(A1);
                float s_r = wr * unpk_hi(A1), s_m = wm * unpk_lo(C1);
                dm01 += (v2f){s_r, s_r} * (v2f){a1.x, a1.y} +
                        (v2f){s_m, s_m} * (v2f){unpk_lo(B1), unpk_hi(B1)};
                dm2  += s_r * a1.z + s_m * unpk_hi(C1);
            }
        }
        if (e < re) {   // tail edge
            int j = __builtin_amdgcn_readfirstlane(idx_j[e]);
            const unsigned int* Pj = P + (size_t)j * 384;
            unsigned int A = Pj[f], B = Pj[128 + f], C = Pj[256 + f];
            const float4* g4 = (const float4*)(geom + (size_t)e * 24);
            float4 a  = g4[0];
            float4 p0 = g4[1], p1 = g4[2], p2 = g4[3], p3 = g4[4], p4 = g4[5];
            v2f ph[N_RBF / 2] = {
                (v2f){p0.x, p0.y}, (v2f){p0.z, p0.w},
                (v2f){p1.x, p1.y}, (v2f){p1.z, p1.w},
                (v2f){p2.x, p2.y}, (v2f){p2.z, p2.w},
                (v2f){p3.x, p3.y}, (v2f){p3.z, p3.w},
                (v2f){p4.x, p4.y}, (v2f){p4.z, p4.w}};
            v2f aq = (v2f){0.f, 0.f}, ar = (v2f){0.f, 0.f}, am = (v2f){0.f, 0.f};
#pragma unroll
            for (int k = 0; k < N_RBF / 2; k++) {
                aq += ph[k] * W0p[k];
                ar += ph[k] * W1p[k];
                am += ph[k] * W2p[k];
            }
            float wq = aq.x + aq.y + a.w * bf0;
            float wr = ar.x + ar.y + a.w * bf1;
            float wm = am.x + am.y + a.w * bf2;
            dq += wq * unpk_lo(A);
            float s_r = wr * unpk_hi(A), s_m = wm * unpk_lo(C);
            dm01 += (v2f){s_r, s_r} * (v2f){a.x, a.y} +
                    (v2f){s_m, s_m} * (v2f){unpk_lo(B), unpk_hi(B)};
            dm2  += s_r * a.z + s_m * unpk_hi(C);
        }

        if (sub == 1) { red[0][f] = dq; red[1][f] = dm01.x; red[2][f] = dm01.y; red[3][f] = dm2; }
        __syncthreads();
        if (sub == 0) {
            dq += red[0][f];
            float d0 = dm01.x + red[1][f], d1 = dm01.y + red[2][f];
            dm2 += red[3][f];
            q[(size_t)i * 128 + f] += dq;
            size_t base = (size_t)i * 384;
            muD[base + f]       += d0;
            muD[base + 128 + f] += d1;
            muD[base + 256 + f] += dm2;
        }
        __syncthreads();
    }
}

// ---------------------------------------------------------------------------
// Fused mixing(l) + node-message(l+1) kernel (unchanged from R9).
__global__ __launch_bounds__(256) void k_mix_fused(
        float* __restrict__ q, float* __restrict__ mu,
        const unsigned short* __restrict__ muxWt,   // [256][128] bf16 (c,k)
        const unsigned short* __restrict__ W1t,     // [128][256]
        const unsigned short* __restrict__ W2t,     // [384][128]
        const float* __restrict__ b1,
        const float* __restrict__ b2,
        const unsigned short* __restrict__ niW1t,   // next-layer node W1t
        const float* __restrict__ nib1,
        const unsigned short* __restrict__ niW2t,   // next-layer node W2t
        const float* __restrict__ nib2,
        int has_node,
        unsigned int* __restrict__ P, int N) {
    __shared__ unsigned short A[16 * 264];          // [node][K=256+pad] bf16
    __shared__ unsigned short Wsp[3 * 16 * 136];    // mu_W bf16; reused as Ah
    __shared__ float Xs[16 * 396];
    __shared__ float Ss[16 * 140];
    int t = threadIdx.x;
    int w = t >> 6, l = t & 63, quad = l >> 4, c0 = l & 15;
    int n0 = blockIdx.x * 16;

#pragma unroll
    for (int i = 0; i < 4; i++) {
        int flat = i * 256 + t;
        int node = flat >> 6, cp = flat & 63;
        int gn = n0 + node;
        unsigned int v = 0u;
        if (gn < N) { const float* s = q + (size_t)gn * 128 + 2 * cp; v = pack_bf2(s[0], s[1]); }
        *(unsigned int*)&A[node * 264 + 2 * cp] = v;
    }

    f32x4 vn2[2], S[2];
#pragma unroll
    for (int jj = 0; jj < 2; jj++) { vn2[jj] = (f32x4){0,0,0,0}; S[jj] = (f32x4){0,0,0,0}; }

    for (int c = 0; c < 3; c++) {
#pragma unroll
        for (int i = 0; i < 4; i++) {
            int flat = i * 256 + t;
            int node = flat >> 6, cp = flat & 63;
            int gn = n0 + node;
            unsigned int v = 0u;
            if (gn < N) {
                const float* s = mu + (size_t)gn * 384 + c * 128 + 2 * cp;
                v = pack_bf2(s[0], s[1]);
            }
            *(unsigned int*)&A[node * 264 + 128 + 2 * cp] = v;
        }
        __syncthreads();
        bf16x8 af[4];
#pragma unroll
        for (int ks = 0; ks < 4; ks++)
            af[ks] = *(const bf16x8*)&A[c0 * 264 + 128 + ks * 32 + quad * 8];
#pragma unroll
        for (int jj = 0; jj < 2; jj++) {
            int jv = 2 * w + jj;
            f32x4 V = (f32x4){0,0,0,0}, Wm = (f32x4){0,0,0,0};
#pragma unroll
            for (int ks = 0; ks < 4; ks++) {
                bf16x8 bV = *(const bf16x8*)&muxWt[(16 * jv + c0) * 128 + ks * 32 + quad * 8];
                V = __builtin_amdgcn_mfma_f32_16x16x32_bf16(af[ks], bV, V, 0, 0, 0);
            }
#pragma unroll
            for (int ks = 0; ks < 4; ks++) {
                bf16x8 bW = *(const bf16x8*)&muxWt[(16 * (jv + 8) + c0) * 128 + ks * 32 + quad * 8];
                Wm = __builtin_amdgcn_mfma_f32_16x16x32_bf16(af[ks], bW, Wm, 0, 0, 0);
            }
            vn2[jj] += V * V;
            S[jj]   += V * Wm;
#pragma unroll
            for (int r = 0; r < 4; r++)
                Wsp[c * 2176 + (quad * 4 + r) * 136 + 16 * jv + c0] =
                    (unsigned short)bf16_rtne(Wm[r]);
        }
        __syncthreads();
    }

#pragma unroll
    for (int jj = 0; jj < 2; jj++) {
        int jv = 2 * w + jj;
#pragma unroll
        for (int r = 0; r < 4; r++)
            A[(quad * 4 + r) * 264 + 128 + 16 * jv + c0] =
                (unsigned short)bf16_rtne(sqrtf(vn2[jj][r] + 1e-8f));
    }
    __syncthreads();

    bf16x8 a2[8];
#pragma unroll
    for (int ks = 0; ks < 8; ks++)
        a2[ks] = *(const bf16x8*)&A[c0 * 264 + ks * 32 + quad * 8];
    {
        unsigned short htmp[2][4];
#pragma unroll
        for (int jj = 0; jj < 2; jj++) {
            int jg = 2 * w + jj;
            float bb = b1[16 * jg + c0];
            f32x4 acc = (f32x4){bb, bb, bb, bb};
#pragma unroll
            for (int ks = 0; ks < 8; ks++) {
                bf16x8 b = *(const bf16x8*)&W1t[(16 * jg + c0) * 256 + ks * 32 + quad * 8];
                acc = __builtin_amdgcn_mfma_f32_16x16x32_bf16(a2[ks], b, acc, 0, 0, 0);
            }
#pragma unroll
            for (int r = 0; r < 4; r++) {
                float aa = acc[r];
                htmp[jj][r] = (unsigned short)bf16_rtne(aa / (1.f + __expf(-aa)));
            }
        }
        __syncthreads();
#pragma unroll
        for (int jj = 0; jj < 2; jj++) {
            int jg = 2 * w + jj;
#pragma unroll
            for (int r = 0; r < 4; r++)
                A[(quad * 4 + r) * 264 + 128 + 16 * jg + c0] = htmp[jj][r];
        }
    }
    __syncthreads();

    bf16x8 a3[4];
#pragma unroll
    for (int ks = 0; ks < 4; ks++)
        a3[ks] = *(const bf16x8*)&A[c0 * 264 + 128 + ks * 32 + quad * 8];
#pragma unroll
    for (int jj = 0; jj < 6; jj++) {
        int jx = 6 * w + jj;
        float bb = b2[16 * jx + c0];
        f32x4 acc = (f32x4){bb, bb, bb, bb};
#pragma unroll
        for (int ks = 0; ks < 4; ks++) {
            bf16x8 b = *(const bf16x8*)&W2t[(16 * jx + c0) * 128 + ks * 32 + quad * 8];
            acc = __builtin_amdgcn_mfma_f32_16x16x32_bf16(a3[ks], b, acc, 0, 0, 0);
        }
#pragma unroll
        for (int r = 0; r < 4; r++)
            Xs[(quad * 4 + r) * 396 + 16 * jx + c0] = acc[r];
    }
#pragma unroll
    for (int jj = 0; jj < 2; jj++) {
        int jv = 2 * w + jj;
#pragma unroll
        for (int r = 0; r < 4; r++)
            Ss[(quad * 4 + r) * 140 + 16 * jv + c0] = S[jj][r];
    }
    __syncthreads();

    int n = t >> 4, fi = (t & 15) * 8;
    int gn = n0 + n;
    if (gn < N) {
        float* qp = q + (size_t)gn * 128 + fi;
        float qn[8];
#pragma unroll
        for (int k = 0; k < 8; k++) {
            qn[k] = qp[k] + Xs[n * 396 + fi + k] +
                    Xs[n * 396 + 256 + fi + k] * Ss[n * 140 + fi + k];
            qp[k] = qn[k];
        }
        unsigned int qd[4];
#pragma unroll
        for (int p = 0; p < 4; p++) qd[p] = pack_bf2(qn[2 * p], qn[2 * p + 1]);
        *(uint4*)&A[n * 264 + fi] = make_uint4(qd[0], qd[1], qd[2], qd[3]);

        size_t base = (size_t)gn * 384;
        float m[3][8];
#pragma unroll
        for (int c = 0; c < 3; c++) {
            float* mp = mu + base + c * 128 + fi;
#pragma unroll
            for (int k = 0; k < 8; k++) {
                m[c][k] = mp[k] + Xs[n * 396 + 128 + fi + k] *
                                  bf16_to_f(Wsp[c * 2176 + n * 136 + fi + k]);
                mp[k] = m[c][k];
            }
        }
        unsigned int d[8];
#pragma unroll
        for (int k = 0; k < 8; k++) {
            d[k] = pack_bf2(m[0][k], m[1][k]);
            ((unsigned short*)&P[base + 256 + fi + k])[1] = (unsigned short)bf16_rtne(m[2][k]);
        }
        *(uint4*)&P[base + 128 + fi]     = make_uint4(d[0], d[1], d[2], d[3]);
        *(uint4*)&P[base + 128 + fi + 4] = make_uint4(d[4], d[5], d[6], d[7]);
    }
    __syncthreads();

    if (has_node) {
        unsigned short* Ah = Wsp;
        bf16x8 a1[4];
#pragma unroll
        for (int ks = 0; ks < 4; ks++)
            a1[ks] = *(const bf16x8*)&A[c0 * 264 + ks * 32 + quad * 8];
#pragma unroll
        for (int jj = 0; jj < 2; jj++) {
            int jg = 2 * w + jj;
            float bb = nib1[16 * jg + c0];
            f32x4 acc = (f32x4){bb, bb, bb, bb};
#pragma unroll
            for (int ks = 0; ks < 4; ks++) {
                bf16x8 b = *(const bf16x8*)&niW1t[(16 * jg + c0) * 128 + ks * 32 + quad * 8];
                acc = __builtin_amdgcn_mfma_f32_16x16x32_bf16(a1[ks], b, acc, 0, 0, 0);
            }
#pragma unroll
            for (int r = 0; r < 4; r++) {
                float aa = acc[r];
                Ah[(quad * 4 + r) * 136 + 16 * jg + c0] =
                    (unsigned short)bf16_rtne(aa / (1.f + __expf(-aa)));
            }
        }
        __syncthreads();

        bf16x8 a4[4];
#pragma unroll
        for (int ks = 0; ks < 4; ks++)
            a4[ks] = *(const bf16x8*)&Ah[c0 * 136 + ks * 32 + quad * 8];
#pragma unroll
        for (int jj = 0; jj < 6; jj++) {
            int jx = 6 * w + jj;
            float bb = nib2[16 * jx + c0];
            f32x4 acc = (f32x4){bb, bb, bb, bb};
#pragma unroll
            for (int ks = 0; ks < 4; ks++) {
                bf16x8 b = *(const bf16x8*)&niW2t[(16 * jx + c0) * 128 + ks * 32 + quad * 8];
                acc = __builtin_amdgcn_mfma_f32_16x16x32_bf16(a4[ks], b, acc, 0, 0, 0);
            }
#pragma unroll
            for (int r = 0; r < 4; r++)
                Xs[(quad * 4 + r) * 396 + 16 * jx + c0] = acc[r];
        }
        __syncthreads();

        if (gn < N) {
            size_t base = (size_t)gn * 384;
            unsigned int d[8];
#pragma unroll
            for (int k = 0; k < 8; k++) {
                float x0 = Xs[n * 396 + fi + k];
                float x1 = Xs[n * 396 + 128 + fi + k];
                float x2 = Xs[n * 396 + 256 + fi + k];
                d[k] = pack_bf2(x0, x1);
                ((unsigned short*)&P[base + 256 + fi + k])[0] = (unsigned short)bf16_rtne(x2);
            }
            *(uint4*)&P[base + fi]     = make_uint4(d[0], d[1], d[2], d[3]);
            *(uint4*)&P[base + fi + 4] = make_uint4(d[4], d[5], d[6], d[7]);
        }
    }
}

// ---------------------------------------------------------------------------
extern "C" void kernel_launch(void* const* d_in, const int* in_sizes, int n_in,
                              void* d_out, int out_size, void* d_ws, size_t ws_size,
                              hipStream_t stream) {
    const int*   Z      = (const int*)d_in[0];
    const float* r_ij   = (const float*)d_in[1];
    const int*   idx_i  = (const int*)d_in[2];
    const int*   idx_j  = (const int*)d_in[3];
    const float* emb    = (const float*)d_in[4];
    const float* filt_W = (const float*)d_in[5];
    const float* filt_b = (const float*)d_in[6];
    const float* int_W1 = (const float*)d_in[7];
    const float* int_b1 = (const float*)d_in[8];
    const float* int_W2 = (const float*)d_in[9];
    const float* int_b2 = (const float*)d_in[10];
    const float* mix_W1 = (const float*)d_in[11];
    const float* mix_b1 = (const float*)d_in[12];
    const float* mix_W2 = (const float*)d_in[13];
    const float* mix_b2 = (const float*)d_in[14];
    const float* mux_W  = (const float*)d_in[15];

    int N = in_sizes[0];
    int E = in_sizes[2];

    float* q   = (float*)d_out;              // [N,128]  q state (fp32)
    float* muD = q + (size_t)N * 128;        // [N,3,128] mu state (fp32)

    float* ws   = (float*)d_ws;
    float* geom = ws;                            // E*24 fp32
    unsigned int* P = (unsigned int*)(geom + (size_t)E * 24);  // N*384 u32
    int* row_ptr = (int*)(P + (size_t)N * 384);  // N+1
    uintptr_t waddr = (uintptr_t)(row_ptr + N + 1);
    waddr = (waddr + 15) & ~(uintptr_t)15;
    unsigned short* muxWt = (unsigned short*)waddr;   // 3*256*128
    unsigned short* W1t   = muxWt + 98304;            // 3*128*256
    unsigned short* W2t   = W1t + 98304;              // 3*384*128
    unsigned short* iW1t  = W2t + 147456;             // 3*128*128
    unsigned short* iW2t  = iW1t + 49152;             // 3*384*128

    k_rowptr<<<(N + 1 + 255) / 256, 256, 0, stream>>>(idx_i, row_ptr, N, E);
    k_init<<<((size_t)N * 384 + 255) / 256, 256, 0, stream>>>(Z, emb, q, P, muD, N);
    k_geom<<<(E + 255) / 256, 256, 0, stream>>>(r_ij, geom, E);
    k_prep<<<2112, 256, 0, stream>>>(mux_W, mix_W1, mix_W2, int_W1, int_W2,
                                     muxWt, W1t, W2t, iW1t, iW2t);

    int tiles = (N + 15) / 16;
    k_node_mfma<<<tiles, 256, 0, stream>>>(
        q, iW1t, int_b1, iW2t, int_b2, P, N);
    for (int l = 0; l < 3; l++) {
        k_edge<<<(N + NPB - 1) / NPB, 256, 0, stream>>>(
            P, geom, idx_j, row_ptr, filt_W, filt_b, l, q, muD, N);
        int nl = (l < 2) ? (l + 1) : 0;
        k_mix_fused<<<tiles, 256, 0, stream>>>(
            q, muD, muxWt + (size_t)l * 32768, W1t + (size_t)l * 32768,
            W2t + (size_t)l * 49152, mix_b1 + l * 128, mix_b2 + l * 384,
            iW1t + (size_t)nl * 16384, int_b1 + nl * 128,
            iW2t + (size_t)nl * 49152, int_b2 + nl * 384,
            (l < 2) ? 1 : 0, P, N);
    }
    // q in d_out; final mu (fp32 state) in muD = d_out mu region.
}

// Round 12
// 576.256 us; speedup vs baseline: 1.0724x; 1.0724x over previous
//
#include <hip/hip_runtime.h>
#include <hip/hip_bf16.h>

#define F_DIM 128
#define N_RBF 20
#define CUTOFF 5.0f
#define PI_F 3.14159265358979323846f
#define NPB 4   // nodes per k_edge block

typedef float v2f __attribute__((ext_vector_type(2)));
typedef __attribute__((ext_vector_type(8))) short bf16x8;
typedef __attribute__((ext_vector_type(4))) float f32x4;

__device__ __forceinline__ unsigned int bf16_rtne(float f) {
    unsigned int u = __float_as_uint(f);
    u += 0x7fffu + ((u >> 16) & 1u);
    return u >> 16;
}
__device__ __forceinline__ unsigned int pack_bf2(float lo, float hi) {
    return bf16_rtne(lo) | (bf16_rtne(hi) << 16);
}
__device__ __forceinline__ float unpk_lo(unsigned int u) {
    return __uint_as_float(u << 16);
}
__device__ __forceinline__ float unpk_hi(unsigned int u) {
    return __uint_as_float(u & 0xffff0000u);
}
__device__ __forceinline__ float bf16_to_f(unsigned short s) {
    return __uint_as_float(((unsigned int)s) << 16);
}

// ---------------------------------------------------------------------------
__global__ __launch_bounds__(256) void k_rowptr(const int* __restrict__ idx_i,
                                                int* __restrict__ row_ptr, int N, int E) {
    int i = blockIdx.x * blockDim.x + threadIdx.x;
    if (i > N) return;
    if (i == N) { row_ptr[N] = E; return; }
    int lo = 0, hi = E;
    while (lo < hi) {
        int mid = (lo + hi) >> 1;
        if (idx_i[mid] < i) lo = mid + 1; else hi = mid;
    }
    row_ptr[i] = lo;
}

// ---------------------------------------------------------------------------
__global__ __launch_bounds__(256) void k_init(const int* __restrict__ Z,
                                              const float* __restrict__ emb,
                                              float* __restrict__ q,
                                              unsigned int* __restrict__ P,
                                              float* __restrict__ muD, int N) {
    int idx = blockIdx.x * blockDim.x + threadIdx.x;
    if (idx < N * F_DIM) {
        int n = idx >> 7, f = idx & 127;
        q[idx] = emb[Z[n] * F_DIM + f];
    }
    if (idx < N * 384) { P[idx] = 0u; muD[idx] = 0.f; }
}

// ---------------------------------------------------------------------------
__global__ __launch_bounds__(256) void k_prep(const float* __restrict__ muxW,
                                              const float* __restrict__ W1,
                                              const float* __restrict__ W2,
                                              const float* __restrict__ iW1,
                                              const float* __restrict__ iW2,
                                              unsigned short* __restrict__ muxWt,
                                              unsigned short* __restrict__ W1t,
                                              unsigned short* __restrict__ W2t,
                                              unsigned short* __restrict__ iW1t,
                                              unsigned short* __restrict__ iW2t) {
    int idx = blockIdx.x * 256 + threadIdx.x;
    if (idx < 98304) {                     // muxWt[l][c<256][k<128]
        int l = idx / 32768, rem = idx % 32768;
        int c = rem / 128, k = rem % 128;
        muxWt[idx] = (unsigned short)bf16_rtne(muxW[l * 32768 + k * 256 + c]);
    } else if (idx < 196608) {             // W1t[l][c<128][k<256]
        int i2 = idx - 98304;
        int l = i2 / 32768, rem = i2 % 32768;
        int c = rem / 256, k = rem % 256;
        W1t[i2] = (unsigned short)bf16_rtne(W1[l * 32768 + k * 128 + c]);
    } else if (idx < 344064) {             // W2t[l][c<384][k<128]
        int i2 = idx - 196608;
        int l = i2 / 49152, rem = i2 % 49152;
        int c = rem / 128, k = rem % 128;
        W2t[i2] = (unsigned short)bf16_rtne(W2[l * 49152 + k * 384 + c]);
    } else if (idx < 393216) {             // iW1t[l][c<128][k<128]
        int i2 = idx - 344064;
        int l = i2 / 16384, rem = i2 % 16384;
        int c = rem / 128, k = rem % 128;
        iW1t[i2] = (unsigned short)bf16_rtne(iW1[l * 16384 + k * 128 + c]);
    } else if (idx < 540672) {             // iW2t[l][c<384][k<128]
        int i2 = idx - 393216;
        int l = i2 / 49152, rem = i2 % 49152;
        int c = rem / 128, k = rem % 128;
        iW2t[i2] = (unsigned short)bf16_rtne(iW2[l * 49152 + k * 384 + c]);
    }
}

// ---------------------------------------------------------------------------
// Packed geometry record: 16 dwords (64 B): [0..3]=dir.xyz,fcut fp32;
// [4..13]=20 bf16 phi*fcut pairs; [14..15] pad.
__global__ __launch_bounds__(256) void k_geom(const float* __restrict__ r,
                                              unsigned int* __restrict__ geom, int E) {
    int e = blockIdx.x * blockDim.x + threadIdx.x;
    if (e >= E) return;
    float x = r[e * 3], y = r[e * 3 + 1], z = r[e * 3 + 2];
    float d = sqrtf(x * x + y * y + z * z);
    float inv = 1.f / d;
    float fc = (d < CUTOFF) ? 0.5f * (__cosf(d * (PI_F / CUTOFF)) + 1.f) : 0.f;
    unsigned int* g = geom + (size_t)e * 16;
    g[0] = __float_as_uint(x * inv);
    g[1] = __float_as_uint(y * inv);
    g[2] = __float_as_uint(z * inv);
    g[3] = __float_as_uint(fc);
    const float delta = CUTOFF / (N_RBF - 1);
    const float coeff = -0.5f / (delta * delta);
    float ph[N_RBF];
#pragma unroll
    for (int k = 0; k < N_RBF; k++) {
        float t = d - k * delta;
        ph[k] = __expf(coeff * t * t) * fc;
    }
#pragma unroll
    for (int k = 0; k < N_RBF / 2; k++)
        g[4 + k] = pack_bf2(ph[2 * k], ph[2 * k + 1]);
}

// ---------------------------------------------------------------------------
// Node message MLP via MFMA (layer 0 only). 4 waves per 16-node tile.
__global__ __launch_bounds__(256) void k_node_mfma(
        const float* __restrict__ q,
        const unsigned short* __restrict__ iW1t,   // [128][128] bf16 (c,k)
        const float* __restrict__ b1,
        const unsigned short* __restrict__ iW2t,   // [384][128]
        const float* __restrict__ b2,
        unsigned int* __restrict__ P, int N) {
    __shared__ unsigned short A[16 * 136];
    __shared__ unsigned short Ah[16 * 136];
    __shared__ float Xs[16 * 396];
    int t = threadIdx.x;
    int w = t >> 6, l = t & 63, quad = l >> 4, c0 = l & 15;
    int n0 = blockIdx.x * 16;

#pragma unroll
    for (int i = 0; i < 4; i++) {
        int flat = i * 256 + t;
        int node = flat >> 6, cp = flat & 63;
        int gn = n0 + node;
        unsigned int v = 0u;
        if (gn < N) { const float* s = q + (size_t)gn * 128 + 2 * cp; v = pack_bf2(s[0], s[1]); }
        *(unsigned int*)&A[node * 136 + 2 * cp] = v;
    }
    __syncthreads();

    bf16x8 a1[4];
#pragma unroll
    for (int ks = 0; ks < 4; ks++)
        a1[ks] = *(const bf16x8*)&A[c0 * 136 + ks * 32 + quad * 8];
#pragma unroll
    for (int jj = 0; jj < 2; jj++) {
        int jg = 2 * w + jj;
        float bb = b1[16 * jg + c0];
        f32x4 acc = (f32x4){bb, bb, bb, bb};
#pragma unroll
        for (int ks = 0; ks < 4; ks++) {
            bf16x8 b = *(const bf16x8*)&iW1t[(16 * jg + c0) * 128 + ks * 32 + quad * 8];
            acc = __builtin_amdgcn_mfma_f32_16x16x32_bf16(a1[ks], b, acc, 0, 0, 0);
        }
#pragma unroll
        for (int r = 0; r < 4; r++) {
            float aa = acc[r];
            Ah[(quad * 4 + r) * 136 + 16 * jg + c0] =
                (unsigned short)bf16_rtne(aa / (1.f + __expf(-aa)));
        }
    }
    __syncthreads();

    bf16x8 a3[4];
#pragma unroll
    for (int ks = 0; ks < 4; ks++)
        a3[ks] = *(const bf16x8*)&Ah[c0 * 136 + ks * 32 + quad * 8];
#pragma unroll
    for (int jj = 0; jj < 6; jj++) {
        int jx = 6 * w + jj;
        float bb = b2[16 * jx + c0];
        f32x4 acc = (f32x4){bb, bb, bb, bb};
#pragma unroll
        for (int ks = 0; ks < 4; ks++) {
            bf16x8 b = *(const bf16x8*)&iW2t[(16 * jx + c0) * 128 + ks * 32 + quad * 8];
            acc = __builtin_amdgcn_mfma_f32_16x16x32_bf16(a3[ks], b, acc, 0, 0, 0);
        }
#pragma unroll
        for (int r = 0; r < 4; r++)
            Xs[(quad * 4 + r) * 396 + 16 * jx + c0] = acc[r];
    }
    __syncthreads();

    int n = t >> 4, fi = (t & 15) * 8;
    int gn = n0 + n;
    if (gn < N) {
        size_t base = (size_t)gn * 384;
        unsigned int d[8];
#pragma unroll
        for (int k = 0; k < 8; k++) {
            float x0 = Xs[n * 396 + fi + k];
            float x1 = Xs[n * 396 + 128 + fi + k];
            float x2 = Xs[n * 396 + 256 + fi + k];
            d[k] = pack_bf2(x0, x1);
            ((unsigned short*)&P[base + 256 + fi + k])[0] = (unsigned short)bf16_rtne(x2);
        }
        *(uint4*)&P[base + fi]     = make_uint4(d[0], d[1], d[2], d[3]);
        *(uint4*)&P[base + fi + 4] = make_uint4(d[4], d[5], d[6], d[7]);
    }
}

// ---------------------------------------------------------------------------
// Edge aggregation (R8-style simple loop — R11 pin/unroll regressed).
// HAS_MU=false (layer 0): mu_j == 0, skip B-plane gather and C-hi term,
// store (not RMW) muD. Bandwidth model: dur ~ fetched bytes.
template <bool HAS_MU>
__global__ __launch_bounds__(256) void k_edge(
        const unsigned int* __restrict__ P,
        const unsigned int* __restrict__ geom,
        const int* __restrict__ idx_j,
        const int* __restrict__ row_ptr,
        const float* __restrict__ filt_W,
        const float* __restrict__ filt_b,
        int layer,
        float* __restrict__ q,
        float* __restrict__ muD, int N) {
    __shared__ float red[4][128];
    int t = threadIdx.x;
    int f = t & 127;
    int sub = __builtin_amdgcn_readfirstlane(t >> 7);

    v2f W0p[N_RBF / 2], W1p[N_RBF / 2], W2p[N_RBF / 2];
    const float* Wbase = filt_W + layer * 384;
#pragma unroll
    for (int j = 0; j < N_RBF / 2; j++) {
        W0p[j] = (v2f){Wbase[(2 * j) * 1152 + f],       Wbase[(2 * j + 1) * 1152 + f]};
        W1p[j] = (v2f){Wbase[(2 * j) * 1152 + 128 + f], Wbase[(2 * j + 1) * 1152 + 128 + f]};
        W2p[j] = (v2f){Wbase[(2 * j) * 1152 + 256 + f], Wbase[(2 * j + 1) * 1152 + 256 + f]};
    }
    float bf0 = filt_b[layer * 384 + f];
    float bf1 = filt_b[layer * 384 + 128 + f];
    float bf2 = filt_b[layer * 384 + 256 + f];

    int i0 = blockIdx.x * NPB;
    for (int nn = 0; nn < NPB; nn++) {
        int i = i0 + nn;
        if (i >= N) break;
        int rs = __builtin_amdgcn_readfirstlane(row_ptr[i]);
        int re = __builtin_amdgcn_readfirstlane(row_ptr[i + 1]);
        float dq = 0.f;
        v2f dm01 = (v2f){0.f, 0.f};
        float dm2 = 0.f;

        for (int e = rs + sub; e < re; e += 2) {
            int j = __builtin_amdgcn_readfirstlane(idx_j[e]);
            const unsigned int* Pj = P + (size_t)j * 384;
            unsigned int A = Pj[f];                       // (xq|xr)
            unsigned int C = Pj[256 + f];                 // (xm|m2)
            unsigned int B = 0;
            if (HAS_MU) B = Pj[128 + f];                  // (m0|m1)

            const unsigned int* g = geom + (size_t)e * 16;
            float dirx = __uint_as_float(g[0]);
            float diry = __uint_as_float(g[1]);
            float dirz = __uint_as_float(g[2]);
            float fcv  = __uint_as_float(g[3]);
            unsigned int pp[10];
#pragma unroll
            for (int k = 0; k < 10; k++) pp[k] = g[4 + k];

            v2f aq = (v2f){0.f, 0.f}, ar = (v2f){0.f, 0.f}, am = (v2f){0.f, 0.f};
#pragma unroll
            for (int k = 0; k < N_RBF / 2; k++) {
                v2f ph = (v2f){unpk_lo(pp[k]), unpk_hi(pp[k])};
                aq += ph * W0p[k];
                ar += ph * W1p[k];
                am += ph * W2p[k];
            }
            float wq = aq.x + aq.y + fcv * bf0;
            float wr = ar.x + ar.y + fcv * bf1;
            float wm = am.x + am.y + fcv * bf2;

            float xq = unpk_lo(A), xr = unpk_hi(A);
            float xm = unpk_lo(C);

            dq += wq * xq;
            float s_r = wr * xr;
            if (HAS_MU) {
                float s_m = wm * xm;
                dm01 += (v2f){s_r, s_r} * (v2f){dirx, diry} +
                        (v2f){s_m, s_m} * (v2f){unpk_lo(B), unpk_hi(B)};
                dm2  += s_r * dirz + s_m * unpk_hi(C);
            } else {
                dm01 += (v2f){s_r, s_r} * (v2f){dirx, diry};
                dm2  += s_r * dirz;
            }
        }

        if (sub == 1) { red[0][f] = dq; red[1][f] = dm01.x; red[2][f] = dm01.y; red[3][f] = dm2; }
        __syncthreads();
        if (sub == 0) {
            dq += red[0][f];
            float d0 = dm01.x + red[1][f], d1 = dm01.y + red[2][f];
            dm2 += red[3][f];
            q[(size_t)i * 128 + f] += dq;
            size_t base = (size_t)i * 384;
            if (HAS_MU) {
                muD[base + f]       += d0;
                muD[base + 128 + f] += d1;
                muD[base + 256 + f] += dm2;
            } else {   // layer 0: mu starts at zero
                muD[base + f]       = d0;
                muD[base + 128 + f] = d1;
                muD[base + 256 + f] = dm2;
            }
        }
        __syncthreads();
    }
}

// ---------------------------------------------------------------------------
// Fused mixing(l) + node-message(l+1) kernel (unchanged from R9).
__global__ __launch_bounds__(256) void k_mix_fused(
        float* __restrict__ q, float* __restrict__ mu,
        const unsigned short* __restrict__ muxWt,   // [256][128] bf16 (c,k)
        const unsigned short* __restrict__ W1t,     // [128][256]
        const unsigned short* __restrict__ W2t,     // [384][128]
        const float* __restrict__ b1,
        const float* __restrict__ b2,
        const unsigned short* __restrict__ niW1t,   // next-layer node W1t
        const float* __restrict__ nib1,
        const unsigned short* __restrict__ niW2t,   // next-layer node W2t
        const float* __restrict__ nib2,
        int has_node,
        unsigned int* __restrict__ P, int N) {
    __shared__ unsigned short A[16 * 264];          // [node][K=256+pad] bf16
    __shared__ unsigned short Wsp[3 * 16 * 136];    // mu_W bf16; reused as Ah
    __shared__ float Xs[16 * 396];
    __shared__ float Ss[16 * 140];
    int t = threadIdx.x;
    int w = t >> 6, l = t & 63, quad = l >> 4, c0 = l & 15;
    int n0 = blockIdx.x * 16;

#pragma unroll
    for (int i = 0; i < 4; i++) {
        int flat = i * 256 + t;
        int node = flat >> 6, cp = flat & 63;
        int gn = n0 + node;
        unsigned int v = 0u;
        if (gn < N) { const float* s = q + (size_t)gn * 128 + 2 * cp; v = pack_bf2(s[0], s[1]); }
        *(unsigned int*)&A[node * 264 + 2 * cp] = v;
    }

    f32x4 vn2[2], S[2];
#pragma unroll
    for (int jj = 0; jj < 2; jj++) { vn2[jj] = (f32x4){0,0,0,0}; S[jj] = (f32x4){0,0,0,0}; }

    for (int c = 0; c < 3; c++) {
#pragma unroll
        for (int i = 0; i < 4; i++) {
            int flat = i * 256 + t;
            int node = flat >> 6, cp = flat & 63;
            int gn = n0 + node;
            unsigned int v = 0u;
            if (gn < N) {
                const float* s = mu + (size_t)gn * 384 + c * 128 + 2 * cp;
                v = pack_bf2(s[0], s[1]);
            }
            *(unsigned int*)&A[node * 264 + 128 + 2 * cp] = v;
        }
        __syncthreads();
        bf16x8 af[4];
#pragma unroll
        for (int ks = 0; ks < 4; ks++)
            af[ks] = *(const bf16x8*)&A[c0 * 264 + 128 + ks * 32 + quad * 8];
#pragma unroll
        for (int jj = 0; jj < 2; jj++) {
            int jv = 2 * w + jj;
            f32x4 V = (f32x4){0,0,0,0}, Wm = (f32x4){0,0,0,0};
#pragma unroll
            for (int ks = 0; ks < 4; ks++) {
                bf16x8 bV = *(const bf16x8*)&muxWt[(16 * jv + c0) * 128 + ks * 32 + quad * 8];
                V = __builtin_amdgcn_mfma_f32_16x16x32_bf16(af[ks], bV, V, 0, 0, 0);
            }
#pragma unroll
            for (int ks = 0; ks < 4; ks++) {
                bf16x8 bW = *(const bf16x8*)&muxWt[(16 * (jv + 8) + c0) * 128 + ks * 32 + quad * 8];
                Wm = __builtin_amdgcn_mfma_f32_16x16x32_bf16(af[ks], bW, Wm, 0, 0, 0);
            }
            vn2[jj] += V * V;
            S[jj]   += V * Wm;
#pragma unroll
            for (int r = 0; r < 4; r++)
                Wsp[c * 2176 + (quad * 4 + r) * 136 + 16 * jv + c0] =
                    (unsigned short)bf16_rtne(Wm[r]);
        }
        __syncthreads();
    }

#pragma unroll
    for (int jj = 0; jj < 2; jj++) {
        int jv = 2 * w + jj;
#pragma unroll
        for (int r = 0; r < 4; r++)
            A[(quad * 4 + r) * 264 + 128 + 16 * jv + c0] =
                (unsigned short)bf16_rtne(sqrtf(vn2[jj][r] + 1e-8f));
    }
    __syncthreads();

    bf16x8 a2[8];
#pragma unroll
    for (int ks = 0; ks < 8; ks++)
        a2[ks] = *(const bf16x8*)&A[c0 * 264 + ks * 32 + quad * 8];
    {
        unsigned short htmp[2][4];
#pragma unroll
        for (int jj = 0; jj < 2; jj++) {
            int jg = 2 * w + jj;
            float bb = b1[16 * jg + c0];
            f32x4 acc = (f32x4){bb, bb, bb, bb};
#pragma unroll
            for (int ks = 0; ks < 8; ks++) {
                bf16x8 b = *(const bf16x8*)&W1t[(16 * jg + c0) * 256 + ks * 32 + quad * 8];
                acc = __builtin_amdgcn_mfma_f32_16x16x32_bf16(a2[ks], b, acc, 0, 0, 0);
            }
#pragma unroll
            for (int r = 0; r < 4; r++) {
                float aa = acc[r];
                htmp[jj][r] = (unsigned short)bf16_rtne(aa / (1.f + __expf(-aa)));
            }
        }
        __syncthreads();
#pragma unroll
        for (int jj = 0; jj < 2; jj++) {
            int jg = 2 * w + jj;
#pragma unroll
            for (int r = 0; r < 4; r++)
                A[(quad * 4 + r) * 264 + 128 + 16 * jg + c0] = htmp[jj][r];
        }
    }
    __syncthreads();

    bf16x8 a3[4];
#pragma unroll
    for (int ks = 0; ks < 4; ks++)
        a3[ks] = *(const bf16x8*)&A[c0 * 264 + 128 + ks * 32 + quad * 8];
#pragma unroll
    for (int jj = 0; jj < 6; jj++) {
        int jx = 6 * w + jj;
        float bb = b2[16 * jx + c0];
        f32x4 acc = (f32x4){bb, bb, bb, bb};
#pragma unroll
        for (int ks = 0; ks < 4; ks++) {
            bf16x8 b = *(const bf16x8*)&W2t[(16 * jx + c0) * 128 + ks * 32 + quad * 8];
            acc = __builtin_amdgcn_mfma_f32_16x16x32_bf16(a3[ks], b, acc, 0, 0, 0);
        }
#pragma unroll
        for (int r = 0; r < 4; r++)
            Xs[(quad * 4 + r) * 396 + 16 * jx + c0] = acc[r];
    }
#pragma unroll
    for (int jj = 0; jj < 2; jj++) {
        int jv = 2 * w + jj;
#pragma unroll
        for (int r = 0; r < 4; r++)
            Ss[(quad * 4 + r) * 140 + 16 * jv + c0] = S[jj][r];
    }
    __syncthreads();

    int n = t >> 4, fi = (t & 15) * 8;
    int gn = n0 + n;
    if (gn < N) {
        float* qp = q + (size_t)gn * 128 + fi;
        float qn[8];
#pragma unroll
        for (int k = 0; k < 8; k++) {
            qn[k] = qp[k] + Xs[n * 396 + fi + k] +
                    Xs[n * 396 + 256 + fi + k] * Ss[n * 140 + fi + k];
            qp[k] = qn[k];
        }
        unsigned int qd[4];
#pragma unroll
        for (int p = 0; p < 4; p++) qd[p] = pack_bf2(qn[2 * p], qn[2 * p + 1]);
        *(uint4*)&A[n * 264 + fi] = make_uint4(qd[0], qd[1], qd[2], qd[3]);

        size_t base = (size_t)gn * 384;
        float m[3][8];
#pragma unroll
        for (int c = 0; c < 3; c++) {
            float* mp = mu + base + c * 128 + fi;
#pragma unroll
            for (int k = 0; k < 8; k++) {
                m[c][k] = mp[k] + Xs[n * 396 + 128 + fi + k] *
                                  bf16_to_f(Wsp[c * 2176 + n * 136 + fi + k]);
                mp[k] = m[c][k];
            }
        }
        unsigned int d[8];
#pragma unroll
        for (int k = 0; k < 8; k++) {
            d[k] = pack_bf2(m[0][k], m[1][k]);
            ((unsigned short*)&P[base + 256 + fi + k])[1] = (unsigned short)bf16_rtne(m[2][k]);
        }
        *(uint4*)&P[base + 128 + fi]     = make_uint4(d[0], d[1], d[2], d[3]);
        *(uint4*)&P[base + 128 + fi + 4] = make_uint4(d[4], d[5], d[6], d[7]);
    }
    __syncthreads();

    if (has_node) {
        unsigned short* Ah = Wsp;
        bf16x8 a1[4];
#pragma unroll
        for (int ks = 0; ks < 4; ks++)
            a1[ks] = *(const bf16x8*)&A[c0 * 264 + ks * 32 + quad * 8];
#pragma unroll
        for (int jj = 0; jj < 2; jj++) {
            int jg = 2 * w + jj;
            float bb = nib1[16 * jg + c0];
            f32x4 acc = (f32x4){bb, bb, bb, bb};
#pragma unroll
            for (int ks = 0; ks < 4; ks++) {
                bf16x8 b = *(const bf16x8*)&niW1t[(16 * jg + c0) * 128 + ks * 32 + quad * 8];
                acc = __builtin_amdgcn_mfma_f32_16x16x32_bf16(a1[ks], b, acc, 0, 0, 0);
            }
#pragma unroll
            for (int r = 0; r < 4; r++) {
                float aa = acc[r];
                Ah[(quad * 4 + r) * 136 + 16 * jg + c0] =
                    (unsigned short)bf16_rtne(aa / (1.f + __expf(-aa)));
            }
        }
        __syncthreads();

        bf16x8 a4[4];
#pragma unroll
        for (int ks = 0; ks < 4; ks++)
            a4[ks] = *(const bf16x8*)&Ah[c0 * 136 + ks * 32 + quad * 8];
#pragma unroll
        for (int jj = 0; jj < 6; jj++) {
            int jx = 6 * w + jj;
            float bb = nib2[16 * jx + c0];
            f32x4 acc = (f32x4){bb, bb, bb, bb};
#pragma unroll
            for (int ks = 0; ks < 4; ks++) {
                bf16x8 b = *(const bf16x8*)&niW2t[(16 * jx + c0) * 128 + ks * 32 + quad * 8];
                acc = __builtin_amdgcn_mfma_f32_16x16x32_bf16(a4[ks], b, acc, 0, 0, 0);
            }
#pragma unroll
            for (int r = 0; r < 4; r++)
                Xs[(quad * 4 + r) * 396 + 16 * jx + c0] = acc[r];
        }
        __syncthreads();

        if (gn < N) {
            size_t base = (size_t)gn * 384;
            unsigned int d[8];
#pragma unroll
            for (int k = 0; k < 8; k++) {
                float x0 = Xs[n * 396 + fi + k];
                float x1 = Xs[n * 396 + 128 + fi + k];
                float x2 = Xs[n * 396 + 256 + fi + k];
                d[k] = pack_bf2(x0, x1);
                ((unsigned short*)&P[base + 256 + fi + k])[0] = (unsigned short)bf16_rtne(x2);
            }
            *(uint4*)&P[base + fi]     = make_uint4(d[0], d[1], d[2], d[3]);
            *(uint4*)&P[base + fi + 4] = make_uint4(d[4], d[5], d[6], d[7]);
        }
    }
}

// ---------------------------------------------------------------------------
extern "C" void kernel_launch(void* const* d_in, const int* in_sizes, int n_in,
                              void* d_out, int out_size, void* d_ws, size_t ws_size,
                              hipStream_t stream) {
    const int*   Z      = (const int*)d_in[0];
    const float* r_ij   = (const float*)d_in[1];
    const int*   idx_i  = (const int*)d_in[2];
    const int*   idx_j  = (const int*)d_in[3];
    const float* emb    = (const float*)d_in[4];
    const float* filt_W = (const float*)d_in[5];
    const float* filt_b = (const float*)d_in[6];
    const float* int_W1 = (const float*)d_in[7];
    const float* int_b1 = (const float*)d_in[8];
    const float* int_W2 = (const float*)d_in[9];
    const float* int_b2 = (const float*)d_in[10];
    const float* mix_W1 = (const float*)d_in[11];
    const float* mix_b1 = (const float*)d_in[12];
    const float* mix_W2 = (const float*)d_in[13];
    const float* mix_b2 = (const float*)d_in[14];
    const float* mux_W  = (const float*)d_in[15];

    int N = in_sizes[0];
    int E = in_sizes[2];

    float* q   = (float*)d_out;              // [N,128]  q state (fp32)
    float* muD = q + (size_t)N * 128;        // [N,3,128] mu state (fp32)

    unsigned int* geom = (unsigned int*)d_ws;                 // E*16 u32 (64 B/edge)
    unsigned int* P = geom + (size_t)E * 16;                  // N*384 u32
    int* row_ptr = (int*)(P + (size_t)N * 384);               // N+1
    uintptr_t waddr = (uintptr_t)(row_ptr + N + 1);
    waddr = (waddr + 15) & ~(uintptr_t)15;
    unsigned short* muxWt = (unsigned short*)waddr;   // 3*256*128
    unsigned short* W1t   = muxWt + 98304;            // 3*128*256
    unsigned short* W2t   = W1t + 98304;              // 3*384*128
    unsigned short* iW1t  = W2t + 147456;             // 3*128*128
    unsigned short* iW2t  = iW1t + 49152;             // 3*384*128

    k_rowptr<<<(N + 1 + 255) / 256, 256, 0, stream>>>(idx_i, row_ptr, N, E);
    k_init<<<((size_t)N * 384 + 255) / 256, 256, 0, stream>>>(Z, emb, q, P, muD, N);
    k_geom<<<(E + 255) / 256, 256, 0, stream>>>(r_ij, geom, E);
    k_prep<<<2112, 256, 0, stream>>>(mux_W, mix_W1, mix_W2, int_W1, int_W2,
                                     muxWt, W1t, W2t, iW1t, iW2t);

    int tiles = (N + 15) / 16;
    k_node_mfma<<<tiles, 256, 0, stream>>>(
        q, iW1t, int_b1, iW2t, int_b2, P, N);
    for (int l = 0; l < 3; l++) {
        if (l == 0)
            k_edge<false><<<(N + NPB - 1) / NPB, 256, 0, stream>>>(
                P, geom, idx_j, row_ptr, filt_W, filt_b, l, q, muD, N);
        else
            k_edge<true><<<(N + NPB - 1) / NPB, 256, 0, stream>>>(
                P, geom, idx_j, row_ptr, filt_W, filt_b, l, q, muD, N);
        int nl = (l < 2) ? (l + 1) : 0;
        k_mix_fused<<<tiles, 256, 0, stream>>>(
            q, muD, muxWt + (size_t)l * 32768, W1t + (size_t)l * 32768,
            W2t + (size_t)l * 49152, mix_b1 + l * 128, mix_b2 + l * 384,
            iW1t + (size_t)nl * 16384, int_b1 + nl * 128,
            iW2t + (size_t)nl * 49152, int_b2 + nl * 384,
            (l < 2) ? 1 : 0, P, N);
    }
    // q in d_out; final mu (fp32 state) in muD = d_out mu region.
}

// Round 13
// 547.149 us; speedup vs baseline: 1.1295x; 1.0532x over previous
//
#include <hip/hip_runtime.h>
#include <hip/hip_bf16.h>
#include <hip/hip_fp16.h>

#define F_DIM 128
#define N_RBF 20
#define CUTOFF 5.0f
#define PI_F 3.14159265358979323846f
#define NPB 4   // nodes per k_edge block

typedef float v2f __attribute__((ext_vector_type(2)));
typedef __attribute__((ext_vector_type(8))) short bf16x8;
typedef __attribute__((ext_vector_type(4))) float f32x4;
typedef _Float16 h2f __attribute__((ext_vector_type(2)));

__device__ __forceinline__ unsigned int bf16_rtne(float f) {
    unsigned int u = __float_as_uint(f);
    u += 0x7fffu + ((u >> 16) & 1u);
    return u >> 16;
}
__device__ __forceinline__ unsigned int pack_bf2(float lo, float hi) {
    return bf16_rtne(lo) | (bf16_rtne(hi) << 16);
}
__device__ __forceinline__ float unpk_lo(unsigned int u) {
    return __uint_as_float(u << 16);
}
__device__ __forceinline__ float unpk_hi(unsigned int u) {
    return __uint_as_float(u & 0xffff0000u);
}
__device__ __forceinline__ float bf16_to_f(unsigned short s) {
    return __uint_as_float(((unsigned int)s) << 16);
}
__device__ __forceinline__ unsigned int pack_h2(float lo, float hi) {
    h2f h = (h2f){(_Float16)lo, (_Float16)hi};
    return __builtin_bit_cast(unsigned int, h);
}
__device__ __forceinline__ float fdot2f(unsigned int a, unsigned int b, float c) {
    h2f ha = __builtin_bit_cast(h2f, a);
    h2f hb = __builtin_bit_cast(h2f, b);
#if __has_builtin(__builtin_amdgcn_fdot2)
    return __builtin_amdgcn_fdot2(ha, hb, c, false);
#else
    return c + (float)ha.x * (float)hb.x + (float)ha.y * (float)hb.y;
#endif
}

// ---------------------------------------------------------------------------
__global__ __launch_bounds__(256) void k_rowptr(const int* __restrict__ idx_i,
                                                int* __restrict__ row_ptr, int N, int E) {
    int i = blockIdx.x * blockDim.x + threadIdx.x;
    if (i > N) return;
    if (i == N) { row_ptr[N] = E; return; }
    int lo = 0, hi = E;
    while (lo < hi) {
        int mid = (lo + hi) >> 1;
        if (idx_i[mid] < i) lo = mid + 1; else hi = mid;
    }
    row_ptr[i] = lo;
}

// ---------------------------------------------------------------------------
__global__ __launch_bounds__(256) void k_init(const int* __restrict__ Z,
                                              const float* __restrict__ emb,
                                              float* __restrict__ q,
                                              unsigned int* __restrict__ P,
                                              float* __restrict__ muD, int N) {
    int idx = blockIdx.x * blockDim.x + threadIdx.x;
    if (idx < N * F_DIM) {
        int n = idx >> 7, f = idx & 127;
        q[idx] = emb[Z[n] * F_DIM + f];
    }
    if (idx < N * 384) { P[idx] = 0u; muD[idx] = 0.f; }
}

// ---------------------------------------------------------------------------
// Weight prep: bf16-transposed MLP weights + f16-pair-packed filter weights.
// filtWh[l][kp<10][c<384] = (f16(Wf[2kp][l*384+c]) | f16(Wf[2kp+1][..]) << 16)
__global__ __launch_bounds__(256) void k_prep(const float* __restrict__ muxW,
                                              const float* __restrict__ W1,
                                              const float* __restrict__ W2,
                                              const float* __restrict__ iW1,
                                              const float* __restrict__ iW2,
                                              const float* __restrict__ filt_W,
                                              unsigned short* __restrict__ muxWt,
                                              unsigned short* __restrict__ W1t,
                                              unsigned short* __restrict__ W2t,
                                              unsigned short* __restrict__ iW1t,
                                              unsigned short* __restrict__ iW2t,
                                              unsigned int* __restrict__ filtWh) {
    int idx = blockIdx.x * 256 + threadIdx.x;
    if (idx < 98304) {                     // muxWt[l][c<256][k<128]
        int l = idx / 32768, rem = idx % 32768;
        int c = rem / 128, k = rem % 128;
        muxWt[idx] = (unsigned short)bf16_rtne(muxW[l * 32768 + k * 256 + c]);
    } else if (idx < 196608) {             // W1t[l][c<128][k<256]
        int i2 = idx - 98304;
        int l = i2 / 32768, rem = i2 % 32768;
        int c = rem / 256, k = rem % 256;
        W1t[i2] = (unsigned short)bf16_rtne(W1[l * 32768 + k * 128 + c]);
    } else if (idx < 344064) {             // W2t[l][c<384][k<128]
        int i2 = idx - 196608;
        int l = i2 / 49152, rem = i2 % 49152;
        int c = rem / 128, k = rem % 128;
        W2t[i2] = (unsigned short)bf16_rtne(W2[l * 49152 + k * 384 + c]);
    } else if (idx < 393216) {             // iW1t[l][c<128][k<128]
        int i2 = idx - 344064;
        int l = i2 / 16384, rem = i2 % 16384;
        int c = rem / 128, k = rem % 128;
        iW1t[i2] = (unsigned short)bf16_rtne(iW1[l * 16384 + k * 128 + c]);
    } else if (idx < 540672) {             // iW2t[l][c<384][k<128]
        int i2 = idx - 393216;
        int l = i2 / 49152, rem = i2 % 49152;
        int c = rem / 128, k = rem % 128;
        iW2t[i2] = (unsigned short)bf16_rtne(iW2[l * 49152 + k * 384 + c]);
    } else if (idx < 552192) {             // filtWh[l][kp<10][c<384]
        int i2 = idx - 540672;
        int l = i2 / 3840, rem = i2 % 3840;
        int kp = rem / 384, c = rem % 384;
        float lo = filt_W[(2 * kp) * 1152 + l * 384 + c];
        float hi = filt_W[(2 * kp + 1) * 1152 + l * 384 + c];
        filtWh[i2] = pack_h2(lo, hi);
    }
}

// ---------------------------------------------------------------------------
// Packed geometry record: 16 dwords (64 B): [0..3]=dir.xyz,fcut fp32;
// [4..13]=20 f16 phi*fcut pairs; [14..15] pad.
__global__ __launch_bounds__(256) void k_geom(const float* __restrict__ r,
                                              unsigned int* __restrict__ geom, int E) {
    int e = blockIdx.x * blockDim.x + threadIdx.x;
    if (e >= E) return;
    float x = r[e * 3], y = r[e * 3 + 1], z = r[e * 3 + 2];
    float d = sqrtf(x * x + y * y + z * z);
    float inv = 1.f / d;
    float fc = (d < CUTOFF) ? 0.5f * (__cosf(d * (PI_F / CUTOFF)) + 1.f) : 0.f;
    unsigned int* g = geom + (size_t)e * 16;
    g[0] = __float_as_uint(x * inv);
    g[1] = __float_as_uint(y * inv);
    g[2] = __float_as_uint(z * inv);
    g[3] = __float_as_uint(fc);
    const float delta = CUTOFF / (N_RBF - 1);
    const float coeff = -0.5f / (delta * delta);
    float ph[N_RBF];
#pragma unroll
    for (int k = 0; k < N_RBF; k++) {
        float t = d - k * delta;
        ph[k] = __expf(coeff * t * t) * fc;
    }
#pragma unroll
    for (int k = 0; k < N_RBF / 2; k++)
        g[4 + k] = pack_h2(ph[2 * k], ph[2 * k + 1]);
}

// ---------------------------------------------------------------------------
// Node message MLP via MFMA (layer 0 only). 4 waves per 16-node tile.
__global__ __launch_bounds__(256) void k_node_mfma(
        const float* __restrict__ q,
        const unsigned short* __restrict__ iW1t,   // [128][128] bf16 (c,k)
        const float* __restrict__ b1,
        const unsigned short* __restrict__ iW2t,   // [384][128]
        const float* __restrict__ b2,
        unsigned int* __restrict__ P, int N) {
    __shared__ unsigned short A[16 * 136];
    __shared__ unsigned short Ah[16 * 136];
    __shared__ float Xs[16 * 396];
    int t = threadIdx.x;
    int w = t >> 6, l = t & 63, quad = l >> 4, c0 = l & 15;
    int n0 = blockIdx.x * 16;

#pragma unroll
    for (int i = 0; i < 4; i++) {
        int flat = i * 256 + t;
        int node = flat >> 6, cp = flat & 63;
        int gn = n0 + node;
        unsigned int v = 0u;
        if (gn < N) { const float* s = q + (size_t)gn * 128 + 2 * cp; v = pack_bf2(s[0], s[1]); }
        *(unsigned int*)&A[node * 136 + 2 * cp] = v;
    }
    __syncthreads();

    bf16x8 a1[4];
#pragma unroll
    for (int ks = 0; ks < 4; ks++)
        a1[ks] = *(const bf16x8*)&A[c0 * 136 + ks * 32 + quad * 8];
#pragma unroll
    for (int jj = 0; jj < 2; jj++) {
        int jg = 2 * w + jj;
        float bb = b1[16 * jg + c0];
        f32x4 acc = (f32x4){bb, bb, bb, bb};
#pragma unroll
        for (int ks = 0; ks < 4; ks++) {
            bf16x8 b = *(const bf16x8*)&iW1t[(16 * jg + c0) * 128 + ks * 32 + quad * 8];
            acc = __builtin_amdgcn_mfma_f32_16x16x32_bf16(a1[ks], b, acc, 0, 0, 0);
        }
#pragma unroll
        for (int r = 0; r < 4; r++) {
            float aa = acc[r];
            Ah[(quad * 4 + r) * 136 + 16 * jg + c0] =
                (unsigned short)bf16_rtne(aa / (1.f + __expf(-aa)));
        }
    }
    __syncthreads();

    bf16x8 a3[4];
#pragma unroll
    for (int ks = 0; ks < 4; ks++)
        a3[ks] = *(const bf16x8*)&Ah[c0 * 136 + ks * 32 + quad * 8];
#pragma unroll
    for (int jj = 0; jj < 6; jj++) {
        int jx = 6 * w + jj;
        float bb = b2[16 * jx + c0];
        f32x4 acc = (f32x4){bb, bb, bb, bb};
#pragma unroll
        for (int ks = 0; ks < 4; ks++) {
            bf16x8 b = *(const bf16x8*)&iW2t[(16 * jx + c0) * 128 + ks * 32 + quad * 8];
            acc = __builtin_amdgcn_mfma_f32_16x16x32_bf16(a3[ks], b, acc, 0, 0, 0);
        }
#pragma unroll
        for (int r = 0; r < 4; r++)
            Xs[(quad * 4 + r) * 396 + 16 * jx + c0] = acc[r];
    }
    __syncthreads();

    int n = t >> 4, fi = (t & 15) * 8;
    int gn = n0 + n;
    if (gn < N) {
        size_t base = (size_t)gn * 384;
        unsigned int d[8];
#pragma unroll
        for (int k = 0; k < 8; k++) {
            float x0 = Xs[n * 396 + fi + k];
            float x1 = Xs[n * 396 + 128 + fi + k];
            float x2 = Xs[n * 396 + 256 + fi + k];
            d[k] = pack_bf2(x0, x1);
            ((unsigned short*)&P[base + 256 + fi + k])[0] = (unsigned short)bf16_rtne(x2);
        }
        *(uint4*)&P[base + fi]     = make_uint4(d[0], d[1], d[2], d[3]);
        *(uint4*)&P[base + fi + 4] = make_uint4(d[4], d[5], d[6], d[7]);
    }
}

// ---------------------------------------------------------------------------
// Edge aggregation. Filter GEMV via packed-f16 v_dot2 (30 fdot2/edge, no
// unpacks). HAS_MU=false (layer 0): skip B and C gathers entirely, store muD.
template <bool HAS_MU>
__global__ __launch_bounds__(256) void k_edge(
        const unsigned int* __restrict__ P,
        const unsigned int* __restrict__ geom,
        const int* __restrict__ idx_j,
        const int* __restrict__ row_ptr,
        const unsigned int* __restrict__ filtWh,   // [10][384] f16-pairs (layer slice)
        const float* __restrict__ filt_b,
        int layer,
        float* __restrict__ q,
        float* __restrict__ muD, int N) {
    __shared__ float red[4][128];
    int t = threadIdx.x;
    int f = t & 127;
    int sub = __builtin_amdgcn_readfirstlane(t >> 7);

    unsigned int Wq[N_RBF / 2], Wr[N_RBF / 2], Wm[N_RBF / 2];
    const unsigned int* Fh = filtWh + layer * 3840;
#pragma unroll
    for (int j = 0; j < N_RBF / 2; j++) {
        Wq[j] = Fh[j * 384 + f];
        Wr[j] = Fh[j * 384 + 128 + f];
        Wm[j] = Fh[j * 384 + 256 + f];
    }
    float bf0 = filt_b[layer * 384 + f];
    float bf1 = filt_b[layer * 384 + 128 + f];
    float bf2 = filt_b[layer * 384 + 256 + f];

    int i0 = blockIdx.x * NPB;
    for (int nn = 0; nn < NPB; nn++) {
        int i = i0 + nn;
        if (i >= N) break;
        int rs = __builtin_amdgcn_readfirstlane(row_ptr[i]);
        int re = __builtin_amdgcn_readfirstlane(row_ptr[i + 1]);
        float dq = 0.f;
        v2f dm01 = (v2f){0.f, 0.f};
        float dm2 = 0.f;

        for (int e = rs + sub; e < re; e += 2) {
            int j = __builtin_amdgcn_readfirstlane(idx_j[e]);
            const unsigned int* Pj = P + (size_t)j * 384;
            unsigned int A = Pj[f];                       // (xq|xr)
            unsigned int B = 0, C = 0;
            if (HAS_MU) { B = Pj[128 + f]; C = Pj[256 + f]; }

            const unsigned int* g = geom + (size_t)e * 16;
            float dirx = __uint_as_float(g[0]);
            float diry = __uint_as_float(g[1]);
            float dirz = __uint_as_float(g[2]);
            float fcv  = __uint_as_float(g[3]);
            unsigned int pp[10];
#pragma unroll
            for (int k = 0; k < 10; k++) pp[k] = g[4 + k];

            float wq = fcv * bf0, wr = fcv * bf1, wm = fcv * bf2;
#pragma unroll
            for (int k = 0; k < N_RBF / 2; k++) {
                wq = fdot2f(pp[k], Wq[k], wq);
                wr = fdot2f(pp[k], Wr[k], wr);
                if (HAS_MU) wm = fdot2f(pp[k], Wm[k], wm);
            }

            float xq = unpk_lo(A), xr = unpk_hi(A);
            dq += wq * xq;
            float s_r = wr * xr;
            if (HAS_MU) {
                float xm = unpk_lo(C);
                float s_m = wm * xm;
                dm01 += (v2f){s_r, s_r} * (v2f){dirx, diry} +
                        (v2f){s_m, s_m} * (v2f){unpk_lo(B), unpk_hi(B)};
                dm2  += s_r * dirz + s_m * unpk_hi(C);
            } else {
                dm01 += (v2f){s_r, s_r} * (v2f){dirx, diry};
                dm2  += s_r * dirz;
            }
        }

        if (sub == 1) { red[0][f] = dq; red[1][f] = dm01.x; red[2][f] = dm01.y; red[3][f] = dm2; }
        __syncthreads();
        if (sub == 0) {
            dq += red[0][f];
            float d0 = dm01.x + red[1][f], d1 = dm01.y + red[2][f];
            dm2 += red[3][f];
            q[(size_t)i * 128 + f] += dq;
            size_t base = (size_t)i * 384;
            if (HAS_MU) {
                muD[base + f]       += d0;
                muD[base + 128 + f] += d1;
                muD[base + 256 + f] += dm2;
            } else {   // layer 0: mu starts at zero
                muD[base + f]       = d0;
                muD[base + 128 + f] = d1;
                muD[base + 256 + f] = dm2;
            }
        }
        __syncthreads();
    }
}

// ---------------------------------------------------------------------------
// Fused mixing(l) + node-message(l+1) kernel (unchanged from R9/R12).
__global__ __launch_bounds__(256) void k_mix_fused(
        float* __restrict__ q, float* __restrict__ mu,
        const unsigned short* __restrict__ muxWt,   // [256][128] bf16 (c,k)
        const unsigned short* __restrict__ W1t,     // [128][256]
        const unsigned short* __restrict__ W2t,     // [384][128]
        const float* __restrict__ b1,
        const float* __restrict__ b2,
        const unsigned short* __restrict__ niW1t,   // next-layer node W1t
        const float* __restrict__ nib1,
        const unsigned short* __restrict__ niW2t,   // next-layer node W2t
        const float* __restrict__ nib2,
        int has_node,
        unsigned int* __restrict__ P, int N) {
    __shared__ unsigned short A[16 * 264];          // [node][K=256+pad] bf16
    __shared__ unsigned short Wsp[3 * 16 * 136];    // mu_W bf16; reused as Ah
    __shared__ float Xs[16 * 396];
    __shared__ float Ss[16 * 140];
    int t = threadIdx.x;
    int w = t >> 6, l = t & 63, quad = l >> 4, c0 = l & 15;
    int n0 = blockIdx.x * 16;

#pragma unroll
    for (int i = 0; i < 4; i++) {
        int flat = i * 256 + t;
        int node = flat >> 6, cp = flat & 63;
        int gn = n0 + node;
        unsigned int v = 0u;
        if (gn < N) { const float* s = q + (size_t)gn * 128 + 2 * cp; v = pack_bf2(s[0], s[1]); }
        *(unsigned int*)&A[node * 264 + 2 * cp] = v;
    }

    f32x4 vn2[2], S[2];
#pragma unroll
    for (int jj = 0; jj < 2; jj++) { vn2[jj] = (f32x4){0,0,0,0}; S[jj] = (f32x4){0,0,0,0}; }

    for (int c = 0; c < 3; c++) {
#pragma unroll
        for (int i = 0; i < 4; i++) {
            int flat = i * 256 + t;
            int node = flat >> 6, cp = flat & 63;
            int gn = n0 + node;
            unsigned int v = 0u;
            if (gn < N) {
                const float* s = mu + (size_t)gn * 384 + c * 128 + 2 * cp;
                v = pack_bf2(s[0], s[1]);
            }
            *(unsigned int*)&A[node * 264 + 128 + 2 * cp] = v;
        }
        __syncthreads();
        bf16x8 af[4];
#pragma unroll
        for (int ks = 0; ks < 4; ks++)
            af[ks] = *(const bf16x8*)&A[c0 * 264 + 128 + ks * 32 + quad * 8];
#pragma unroll
        for (int jj = 0; jj < 2; jj++) {
            int jv = 2 * w + jj;
            f32x4 V = (f32x4){0,0,0,0}, Wm = (f32x4){0,0,0,0};
#pragma unroll
            for (int ks = 0; ks < 4; ks++) {
                bf16x8 bV = *(const bf16x8*)&muxWt[(16 * jv + c0) * 128 + ks * 32 + quad * 8];
                V = __builtin_amdgcn_mfma_f32_16x16x32_bf16(af[ks], bV, V, 0, 0, 0);
            }
#pragma unroll
            for (int ks = 0; ks < 4; ks++) {
                bf16x8 bW = *(const bf16x8*)&muxWt[(16 * (jv + 8) + c0) * 128 + ks * 32 + quad * 8];
                Wm = __builtin_amdgcn_mfma_f32_16x16x32_bf16(af[ks], bW, Wm, 0, 0, 0);
            }
            vn2[jj] += V * V;
            S[jj]   += V * Wm;
#pragma unroll
            for (int r = 0; r < 4; r++)
                Wsp[c * 2176 + (quad * 4 + r) * 136 + 16 * jv + c0] =
                    (unsigned short)bf16_rtne(Wm[r]);
        }
        __syncthreads();
    }

#pragma unroll
    for (int jj = 0; jj < 2; jj++) {
        int jv = 2 * w + jj;
#pragma unroll
        for (int r = 0; r < 4; r++)
            A[(quad * 4 + r) * 264 + 128 + 16 * jv + c0] =
                (unsigned short)bf16_rtne(sqrtf(vn2[jj][r] + 1e-8f));
    }
    __syncthreads();

    bf16x8 a2[8];
#pragma unroll
    for (int ks = 0; ks < 8; ks++)
        a2[ks] = *(const bf16x8*)&A[c0 * 264 + ks * 32 + quad * 8];
    {
        unsigned short htmp[2][4];
#pragma unroll
        for (int jj = 0; jj < 2; jj++) {
            int jg = 2 * w + jj;
            float bb = b1[16 * jg + c0];
            f32x4 acc = (f32x4){bb, bb, bb, bb};
#pragma unroll
            for (int ks = 0; ks < 8; ks++) {
                bf16x8 b = *(const bf16x8*)&W1t[(16 * jg + c0) * 256 + ks * 32 + quad * 8];
                acc = __builtin_amdgcn_mfma_f32_16x16x32_bf16(a2[ks], b, acc, 0, 0, 0);
            }
#pragma unroll
            for (int r = 0; r < 4; r++) {
                float aa = acc[r];
                htmp[jj][r] = (unsigned short)bf16_rtne(aa / (1.f + __expf(-aa)));
            }
        }
        __syncthreads();
#pragma unroll
        for (int jj = 0; jj < 2; jj++) {
            int jg = 2 * w + jj;
#pragma unroll
            for (int r = 0; r < 4; r++)
                A[(quad * 4 + r) * 264 + 128 + 16 * jg + c0] = htmp[jj][r];
        }
    }
    __syncthreads();

    bf16x8 a3[4];
#pragma unroll
    for (int ks = 0; ks < 4; ks++)
        a3[ks] = *(const bf16x8*)&A[c0 * 264 + 128 + ks * 32 + quad * 8];
#pragma unroll
    for (int jj = 0; jj < 6; jj++) {
        int jx = 6 * w + jj;
        float bb = b2[16 * jx + c0];
        f32x4 acc = (f32x4){bb, bb, bb, bb};
#pragma unroll
        for (int ks = 0; ks < 4; ks++) {
            bf16x8 b = *(const bf16x8*)&W2t[(16 * jx + c0) * 128 + ks * 32 + quad * 8];
            acc = __builtin_amdgcn_mfma_f32_16x16x32_bf16(a3[ks], b, acc, 0, 0, 0);
        }
#pragma unroll
        for (int r = 0; r < 4; r++)
            Xs[(quad * 4 + r) * 396 + 16 * jx + c0] = acc[r];
    }
#pragma unroll
    for (int jj = 0; jj < 2; jj++) {
        int jv = 2 * w + jj;
#pragma unroll
        for (int r = 0; r < 4; r++)
            Ss[(quad * 4 + r) * 140 + 16 * jv + c0] = S[jj][r];
    }
    __syncthreads();

    int n = t >> 4, fi = (t & 15) * 8;
    int gn = n0 + n;
    if (gn < N) {
        float* qp = q + (size_t)gn * 128 + fi;
        float qn[8];
#pragma unroll
        for (int k = 0; k < 8; k++) {
            qn[k] = qp[k] + Xs[n * 396 + fi + k] +
                    Xs[n * 396 + 256 + fi + k] * Ss[n * 140 + fi + k];
            qp[k] = qn[k];
        }
        unsigned int qd[4];
#pragma unroll
        for (int p = 0; p < 4; p++) qd[p] = pack_bf2(qn[2 * p], qn[2 * p + 1]);
        *(uint4*)&A[n * 264 + fi] = make_uint4(qd[0], qd[1], qd[2], qd[3]);

        size_t base = (size_t)gn * 384;
        float m[3][8];
#pragma unroll
        for (int c = 0; c < 3; c++) {
            float* mp = mu + base + c * 128 + fi;
#pragma unroll
            for (int k = 0; k < 8; k++) {
                m[c][k] = mp[k] + Xs[n * 396 + 128 + fi + k] *
                                  bf16_to_f(Wsp[c * 2176 + n * 136 + fi + k]);
                mp[k] = m[c][k];
            }
        }
        unsigned int d[8];
#pragma unroll
        for (int k = 0; k < 8; k++) {
            d[k] = pack_bf2(m[0][k], m[1][k]);
            ((unsigned short*)&P[base + 256 + fi + k])[1] = (unsigned short)bf16_rtne(m[2][k]);
        }
        *(uint4*)&P[base + 128 + fi]     = make_uint4(d[0], d[1], d[2], d[3]);
        *(uint4*)&P[base + 128 + fi + 4] = make_uint4(d[4], d[5], d[6], d[7]);
    }
    __syncthreads();

    if (has_node) {
        unsigned short* Ah = Wsp;
        bf16x8 a1[4];
#pragma unroll
        for (int ks = 0; ks < 4; ks++)
            a1[ks] = *(const bf16x8*)&A[c0 * 264 + ks * 32 + quad * 8];
#pragma unroll
        for (int jj = 0; jj < 2; jj++) {
            int jg = 2 * w + jj;
            float bb = nib1[16 * jg + c0];
            f32x4 acc = (f32x4){bb, bb, bb, bb};
#pragma unroll
            for (int ks = 0; ks < 4; ks++) {
                bf16x8 b = *(const bf16x8*)&niW1t[(16 * jg + c0) * 128 + ks * 32 + quad * 8];
                acc = __builtin_amdgcn_mfma_f32_16x16x32_bf16(a1[ks], b, acc, 0, 0, 0);
            }
#pragma unroll
            for (int r = 0; r < 4; r++) {
                float aa = acc[r];
                Ah[(quad * 4 + r) * 136 + 16 * jg + c0] =
                    (unsigned short)bf16_rtne(aa / (1.f + __expf(-aa)));
            }
        }
        __syncthreads();

        bf16x8 a4[4];
#pragma unroll
        for (int ks = 0; ks < 4; ks++)
            a4[ks] = *(const bf16x8*)&Ah[c0 * 136 + ks * 32 + quad * 8];
#pragma unroll
        for (int jj = 0; jj < 6; jj++) {
            int jx = 6 * w + jj;
            float bb = nib2[16 * jx + c0];
            f32x4 acc = (f32x4){bb, bb, bb, bb};
#pragma unroll
            for (int ks = 0; ks < 4; ks++) {
                bf16x8 b = *(const bf16x8*)&niW2t[(16 * jx + c0) * 128 + ks * 32 + quad * 8];
                acc = __builtin_amdgcn_mfma_f32_16x16x32_bf16(a4[ks], b, acc, 0, 0, 0);
            }
#pragma unroll
            for (int r = 0; r < 4; r++)
                Xs[(quad * 4 + r) * 396 + 16 * jx + c0] = acc[r];
        }
        __syncthreads();

        if (gn < N) {
            size_t base = (size_t)gn * 384;
            unsigned int d[8];
#pragma unroll
            for (int k = 0; k < 8; k++) {
                float x0 = Xs[n * 396 + fi + k];
                float x1 = Xs[n * 396 + 128 + fi + k];
                float x2 = Xs[n * 396 + 256 + fi + k];
                d[k] = pack_bf2(x0, x1);
                ((unsigned short*)&P[base + 256 + fi + k])[0] = (unsigned short)bf16_rtne(x2);
            }
            *(uint4*)&P[base + fi]     = make_uint4(d[0], d[1], d[2], d[3]);
            *(uint4*)&P[base + fi + 4] = make_uint4(d[4], d[5], d[6], d[7]);
        }
    }
}

// ---------------------------------------------------------------------------
extern "C" void kernel_launch(void* const* d_in, const int* in_sizes, int n_in,
                              void* d_out, int out_size, void* d_ws, size_t ws_size,
                              hipStream_t stream) {
    const int*   Z      = (const int*)d_in[0];
    const float* r_ij   = (const float*)d_in[1];
    const int*   idx_i  = (const int*)d_in[2];
    const int*   idx_j  = (const int*)d_in[3];
    const float* emb    = (const float*)d_in[4];
    const float* filt_W = (const float*)d_in[5];
    const float* filt_b = (const float*)d_in[6];
    const float* int_W1 = (const float*)d_in[7];
    const float* int_b1 = (const float*)d_in[8];
    const float* int_W2 = (const float*)d_in[9];
    const float* int_b2 = (const float*)d_in[10];
    const float* mix_W1 = (const float*)d_in[11];
    const float* mix_b1 = (const float*)d_in[12];
    const float* mix_W2 = (const float*)d_in[13];
    const float* mix_b2 = (const float*)d_in[14];
    const float* mux_W  = (const float*)d_in[15];

    int N = in_sizes[0];
    int E = in_sizes[2];

    float* q   = (float*)d_out;              // [N,128]  q state (fp32)
    float* muD = q + (size_t)N * 128;        // [N,3,128] mu state (fp32)

    unsigned int* geom = (unsigned int*)d_ws;                 // E*16 u32 (64 B/edge)
    unsigned int* P = geom + (size_t)E * 16;                  // N*384 u32
    int* row_ptr = (int*)(P + (size_t)N * 384);               // N+1
    uintptr_t waddr = (uintptr_t)(row_ptr + N + 1);
    waddr = (waddr + 15) & ~(uintptr_t)15;
    unsigned short* muxWt = (unsigned short*)waddr;   // 3*256*128
    unsigned short* W1t   = muxWt + 98304;            // 3*128*256
    unsigned short* W2t   = W1t + 98304;              // 3*384*128
    unsigned short* iW1t  = W2t + 147456;             // 3*128*128
    unsigned short* iW2t  = iW1t + 49152;             // 3*384*128
    unsigned int* filtWh  = (unsigned int*)(iW2t + 147456);   // 3*10*384 u32

    k_rowptr<<<(N + 1 + 255) / 256, 256, 0, stream>>>(idx_i, row_ptr, N, E);
    k_init<<<((size_t)N * 384 + 255) / 256, 256, 0, stream>>>(Z, emb, q, P, muD, N);
    k_geom<<<(E + 255) / 256, 256, 0, stream>>>(r_ij, geom, E);
    k_prep<<<2157, 256, 0, stream>>>(mux_W, mix_W1, mix_W2, int_W1, int_W2, filt_W,
                                     muxWt, W1t, W2t, iW1t, iW2t, filtWh);

    int tiles = (N + 15) / 16;
    k_node_mfma<<<tiles, 256, 0, stream>>>(
        q, iW1t, int_b1, iW2t, int_b2, P, N);
    for (int l = 0; l < 3; l++) {
        if (l == 0)
            k_edge<false><<<(N + NPB - 1) / NPB, 256, 0, stream>>>(
                P, geom, idx_j, row_ptr, filtWh, filt_b, l, q, muD, N);
        else
            k_edge<true><<<(N + NPB - 1) / NPB, 256, 0, stream>>>(
                P, geom, idx_j, row_ptr, filtWh, filt_b, l, q, muD, N);
        int nl = (l < 2) ? (l + 1) : 0;
        k_mix_fused<<<tiles, 256, 0, stream>>>(
            q, muD, muxWt + (size_t)l * 32768, W1t + (size_t)l * 32768,
            W2t + (size_t)l * 49152, mix_b1 + l * 128, mix_b2 + l * 384,
            iW1t + (size_t)nl * 16384, int_b1 + nl * 128,
            iW2t + (size_t)nl * 49152, int_b2 + nl * 384,
            (l < 2) ? 1 : 0, P, N);
    }
    // q in d_out; final mu (fp32 state) in muD = d_out mu region.
}